// Round 1
// baseline (374.186 us; speedup 1.0000x reference)
//
#include <hip/hip_runtime.h>

// Problem constants (match reference)
#define H_  1024
#define W_  2048
#define HP  1026                 // H+2
#define WP  2050                 // W+2
#define GRID_F (HP*WP)           // 2,103,300 cells = 8.41 MB fp32

// ws layout (float units)
#define MASK_OFFF  2103360                  // byte-mask (GRID_F bytes) lives here
#define STATS_OFFF (MASK_OFFF + 525888)     // 54 moment accumulators
#define ZERO_FLOATS (STATS_OFFF + 64)       // memset extent

typedef float fvec4 __attribute__((ext_vector_type(4)));

// ---------------------------------------------------------------- scatter
// Write feature value into dense padded grid + set 1-byte active mask.
__global__ __launch_bounds__(256) void scatter_k(
    const float* __restrict__ feats, const int2* __restrict__ coords,
    float* __restrict__ grid, unsigned char* __restrict__ mask, int N)
{
    int i = blockIdx.x * 256 + threadIdx.x;
    if (i >= N) return;
    int2 c = coords[i];                       // c.x = y, c.y = x
    int cell = (c.x + 1) * WP + (c.y + 1);
    grid[cell] = feats[i];
    mask[cell] = 1;
}

// ---------------------------------------------------------------- stats
// Dense row-order pass: s[k] = sum over active cells of window val k (9),
// M[k][l] upper-tri second moments (45) -> 54 floats. All loads coalesced.
__global__ __launch_bounds__(256) void stats_dense_k(
    const float* __restrict__ grid, const unsigned char* __restrict__ mask,
    float* __restrict__ stats)
{
    const int off[9] = {-WP-1, -WP, -WP+1, -1, 0, 1, WP-1, WP, WP+1};
    float acc[54];
    #pragma unroll
    for (int j = 0; j < 54; ++j) acc[j] = 0.f;

    int stride = gridDim.x * blockDim.x;
    for (int c = blockIdx.x * blockDim.x + threadIdx.x; c < GRID_F; c += stride) {
        if (mask[c]) {                        // active center
            float p[9];
            #pragma unroll
            for (int k = 0; k < 9; ++k) p[k] = grid[c + off[k]];
            #pragma unroll
            for (int k = 0; k < 9; ++k) acc[k] += p[k];
            int t = 9;
            #pragma unroll
            for (int k = 0; k < 9; ++k)
                #pragma unroll
                for (int l = k; l < 9; ++l) acc[t++] += p[k] * p[l];
        }
    }

    __shared__ float part[4][54];
    int wave = threadIdx.x >> 6, lane = threadIdx.x & 63;
    #pragma unroll
    for (int j = 0; j < 54; ++j) {
        float v = acc[j];
        #pragma unroll
        for (int d = 32; d > 0; d >>= 1) v += __shfl_down(v, d, 64);
        if (lane == 0) part[wave][j] = v;
    }
    __syncthreads();
    if (threadIdx.x < 54) {
        float v = part[0][threadIdx.x] + part[1][threadIdx.x]
                + part[2][threadIdx.x] + part[3][threadIdx.x];
        atomicAdd(&stats[threadIdx.x], v);
    }
}

// ---------------------------------------------------------------- output
// Point-order pass: 16 lanes per point, 4 points per wave.
// Lanes 0..8 of each group gather the 3x3 window (random reads, grid is
// L2/L3-resident); broadcast via shuffle; 64 channels per point via
// register-held weights; stores are fully sequential 1KB/wave nontemporal.
// BN finalize (scale/shift from raw moments) fused into the prologue.
__global__ __launch_bounds__(256) void out_point_k(
    const float* __restrict__ grid, const int2* __restrict__ coords,
    const float* __restrict__ w, const float* __restrict__ stats,
    const float* __restrict__ gamma, const float* __restrict__ beta,
    float* __restrict__ out, int N)
{
    __shared__ __align__(16) float sc_s[64];
    __shared__ __align__(16) float sh_s[64];

    int t = threadIdx.x;
    if (t < 64) {                              // fused finalize (per-block, L2-hit)
        int c = t;
        float invN = 1.0f / (float)N;
        float wc[9];
        #pragma unroll
        for (int k = 0; k < 9; ++k) wc[k] = w[k * 64 + c];
        float mean = 0.f;
        #pragma unroll
        for (int k = 0; k < 9; ++k) mean += stats[k] * invN * wc[k];
        float e2 = 0.f;
        int s = 9;
        #pragma unroll
        for (int k = 0; k < 9; ++k)
            #pragma unroll
            for (int l = k; l < 9; ++l) {
                float mm = stats[s++] * invN;
                e2 += (k == l ? 1.f : 2.f) * wc[k] * wc[l] * mm;
            }
        float var = e2 - mean * mean;
        float sc = gamma[c] * rsqrtf(var + 1e-5f);
        sc_s[c] = sc;
        sh_s[c] = beta[c] - mean * sc;
    }
    __syncthreads();

    int lane = t & 63;
    int q    = lane & 15;                      // channel quad 0..15
    int grp  = lane & 48;                      // group base lane (16-lane groups)

    // per-lane gather offset (valid only for q < 9)
    int dy = q / 3, dx = q - dy * 3;
    int offq = (dy - 1) * WP + (dx - 1);

    // weights for this lane's 4 channels, held in registers (36 VGPRs)
    const fvec4* w4 = (const fvec4*)w;         // [9][16]
    fvec4 wq[9];
    #pragma unroll
    for (int k = 0; k < 9; ++k) wq[k] = w4[k * 16 + q];
    fvec4 sc4 = ((const fvec4*)sc_s)[q];
    fvec4 sh4 = ((const fvec4*)sh_s)[q];

    fvec4* out4 = (fvec4*)out;
    int gwave = (blockIdx.x * 256 + t) >> 6;
    int pt0   = gwave * 4 + (lane >> 4);
    int pstep = (gridDim.x * 256) >> 4;        // points per sweep

    for (int pt = pt0; pt < N; pt += pstep) {
        int2 cxy = coords[pt];                 // same addr across group -> broadcast
        int cell = (cxy.x + 1) * WP + (cxy.y + 1);
        float v = 0.f;
        if (q < 9) v = grid[cell + offq];      // 9 lanes gather the window
        fvec4 acc = {0.f, 0.f, 0.f, 0.f};
        #pragma unroll
        for (int k = 0; k < 9; ++k) {
            float pk = __shfl(v, grp + k, 64); // broadcast window val k to group
            acc.x = fmaf(pk, wq[k].x, acc.x);
            acc.y = fmaf(pk, wq[k].y, acc.y);
            acc.z = fmaf(pk, wq[k].z, acc.z);
            acc.w = fmaf(pk, wq[k].w, acc.w);
        }
        acc.x = fmaxf(fmaf(acc.x, sc4.x, sh4.x), 0.f);
        acc.y = fmaxf(fmaf(acc.y, sc4.y, sh4.y), 0.f);
        acc.z = fmaxf(fmaf(acc.z, sc4.z, sh4.z), 0.f);
        acc.w = fmaxf(fmaf(acc.w, sc4.w, sh4.w), 0.f);
        __builtin_nontemporal_store(acc, &out4[(long)pt * 16 + q]);  // 1KB/wave, sequential
    }
}

// ---------------------------------------------------------------- launch
extern "C" void kernel_launch(void* const* d_in, const int* in_sizes, int n_in,
                              void* d_out, int out_size, void* d_ws, size_t ws_size,
                              hipStream_t stream)
{
    const float* feats  = (const float*)d_in[0];
    const float* weight = (const float*)d_in[1];   // [9][1][64]
    const float* gamma  = (const float*)d_in[2];
    const float* beta   = (const float*)d_in[3];
    const int2*  coords = (const int2*)d_in[4];    // [N][2] (y,x)
    float*       out    = (float*)d_out;
    int N = in_sizes[0];                           // C_IN == 1

    float*         ws    = (float*)d_ws;
    float*         grid  = ws;
    unsigned char* mask  = (unsigned char*)(ws + MASK_OFFF);
    float*         stats = ws + STATS_OFFF;

    // zero grid + mask + stats accumulators (ws is poisoned 0xAA)
    (void)hipMemsetAsync(d_ws, 0, (size_t)ZERO_FLOATS * sizeof(float), stream);

    scatter_k    <<<(N + 255) / 256, 256, 0, stream>>>(feats, coords, grid, mask, N);
    stats_dense_k<<<1024, 256, 0, stream>>>(grid, mask, stats);
    out_point_k  <<<4096, 256, 0, stream>>>(grid, coords, weight, stats, gamma, beta, out, N);
}

// Round 3
// 371.056 us; speedup vs baseline: 1.0084x; 1.0084x over previous
//
#include <hip/hip_runtime.h>

// Problem constants (match reference)
#define H_  1024
#define W_  2048
#define HP  1026                 // H+2
#define WP  2050                 // W+2
#define GRID_F (HP*WP)           // 2,103,300 cells = 8.41 MB fp32

// ws layout (float units)
#define MASK_OFFF  2103360                  // byte-mask (GRID_F bytes) lives here
#define STATS_OFFF (MASK_OFFF + 525888)     // 54 moment accumulators
#define ZERO_FLOATS (STATS_OFFF + 64)       // memset extent

typedef float fvec4 __attribute__((ext_vector_type(4)));

// ---------------------------------------------------------------- scatter
// Write feature value into dense padded grid + set 1-byte active mask.
__global__ __launch_bounds__(256) void scatter_k(
    const float* __restrict__ feats, const int2* __restrict__ coords,
    float* __restrict__ grid, unsigned char* __restrict__ mask, int N)
{
    int i = blockIdx.x * 256 + threadIdx.x;
    if (i >= N) return;
    int2 c = coords[i];                       // c.x = y, c.y = x
    int cell = (c.x + 1) * WP + (c.y + 1);
    grid[cell] = feats[i];
    mask[cell] = 1;
}

// ---------------------------------------------------------------- stats
// Dense row-order pass: s[k] = sum over active cells of window val k (9),
// M[k][l] upper-tri second moments (45) -> 54 floats. All loads coalesced.
__global__ __launch_bounds__(256) void stats_dense_k(
    const float* __restrict__ grid, const unsigned char* __restrict__ mask,
    float* __restrict__ stats)
{
    const int off[9] = {-WP-1, -WP, -WP+1, -1, 0, 1, WP-1, WP, WP+1};
    float acc[54];
    #pragma unroll
    for (int j = 0; j < 54; ++j) acc[j] = 0.f;

    int stride = gridDim.x * blockDim.x;
    for (int c = blockIdx.x * blockDim.x + threadIdx.x; c < GRID_F; c += stride) {
        if (mask[c]) {                        // active center
            float p[9];
            #pragma unroll
            for (int k = 0; k < 9; ++k) p[k] = grid[c + off[k]];
            #pragma unroll
            for (int k = 0; k < 9; ++k) acc[k] += p[k];
            int t = 9;
            #pragma unroll
            for (int k = 0; k < 9; ++k)
                #pragma unroll
                for (int l = k; l < 9; ++l) acc[t++] += p[k] * p[l];
        }
    }

    __shared__ float part[4][54];
    int wave = threadIdx.x >> 6, lane = threadIdx.x & 63;
    #pragma unroll
    for (int j = 0; j < 54; ++j) {
        float v = acc[j];
        #pragma unroll
        for (int d = 32; d > 0; d >>= 1) v += __shfl_down(v, d, 64);
        if (lane == 0) part[wave][j] = v;
    }
    __syncthreads();
    if (threadIdx.x < 54) {
        float v = part[0][threadIdx.x] + part[1][threadIdx.x]
                + part[2][threadIdx.x] + part[3][threadIdx.x];
        atomicAdd(&stats[threadIdx.x], v);
    }
}

// ---------------------------------------------------------------- output
// Point-order pass, 4-deep pipelined: 16 lanes per point-slot, each group
// processes 4 points per sweep. All 4 coords loads issue first, then all
// 4 window gathers (independent -> latency overlapped), then 4x compute +
// sequential 1KB/wave nontemporal stores. BN finalize fused in prologue.
__global__ __launch_bounds__(256) void out_point_k(
    const float* __restrict__ grid, const int2* __restrict__ coords,
    const float* __restrict__ w, const float* __restrict__ stats,
    const float* __restrict__ gamma, const float* __restrict__ beta,
    float* __restrict__ out, int N)
{
    __shared__ __align__(16) float sc_s[64];
    __shared__ __align__(16) float sh_s[64];

    int t = threadIdx.x;
    if (t < 64) {                              // fused finalize (per-block, L2-hit)
        int c = t;
        float invN = 1.0f / (float)N;
        float wc[9];
        #pragma unroll
        for (int k = 0; k < 9; ++k) wc[k] = w[k * 64 + c];
        float mean = 0.f;
        #pragma unroll
        for (int k = 0; k < 9; ++k) mean += stats[k] * invN * wc[k];
        float e2 = 0.f;
        int s = 9;
        #pragma unroll
        for (int k = 0; k < 9; ++k)
            #pragma unroll
            for (int l = k; l < 9; ++l) {
                float mm = stats[s++] * invN;
                e2 += (k == l ? 1.f : 2.f) * wc[k] * wc[l] * mm;
            }
        float var = e2 - mean * mean;
        float sc = gamma[c] * rsqrtf(var + 1e-5f);
        sc_s[c] = sc;
        sh_s[c] = beta[c] - mean * sc;
    }
    __syncthreads();

    int lane = t & 63;
    int q    = lane & 15;                      // channel quad 0..15
    int grp  = lane & 48;                      // group base lane (16-lane groups)

    // per-lane gather offset (valid only for q < 9)
    int dy = q / 3, dx = q - dy * 3;
    int offq = (dy - 1) * WP + (dx - 1);

    // weights for this lane's 4 channels, held in registers (36 VGPRs)
    const fvec4* w4 = (const fvec4*)w;         // [9][16]
    fvec4 wq[9];
    #pragma unroll
    for (int k = 0; k < 9; ++k) wq[k] = w4[k * 16 + q];
    fvec4 sc4 = ((const fvec4*)sc_s)[q];
    fvec4 sh4 = ((const fvec4*)sh_s)[q];

    fvec4* out4 = (fvec4*)out;
    int gid = (blockIdx.x * 256 + t) >> 4;     // global 16-lane group id
    int G   = (gridDim.x * 256) >> 4;          // total groups

    for (int S = 0; S < N; S += 4 * G) {
        int pj[4];
        #pragma unroll
        for (int j = 0; j < 4; ++j) pj[j] = S + j * G + gid;

        // ---- load phase: 4 independent coords loads, then 4 gathers
        int2 c4[4];
        #pragma unroll
        for (int j = 0; j < 4; ++j) {
            c4[j].x = 0; c4[j].y = 0;
            if (pj[j] < N) c4[j] = coords[pj[j]];  // uniform addr per group -> broadcast
        }
        float v4[4];
        #pragma unroll
        for (int j = 0; j < 4; ++j) {
            v4[j] = 0.f;
            if (pj[j] < N && q < 9) {
                int cell = (c4[j].x + 1) * WP + (c4[j].y + 1);
                v4[j] = grid[cell + offq];     // 9 lanes gather the window
            }
        }
        // ---- compute + store phase
        #pragma unroll
        for (int j = 0; j < 4; ++j) {
            if (pj[j] < N) {
                fvec4 acc = {0.f, 0.f, 0.f, 0.f};
                #pragma unroll
                for (int k = 0; k < 9; ++k) {
                    float pk = __shfl(v4[j], grp + k, 64);  // broadcast window val k
                    acc.x = fmaf(pk, wq[k].x, acc.x);
                    acc.y = fmaf(pk, wq[k].y, acc.y);
                    acc.z = fmaf(pk, wq[k].z, acc.z);
                    acc.w = fmaf(pk, wq[k].w, acc.w);
                }
                acc.x = fmaxf(fmaf(acc.x, sc4.x, sh4.x), 0.f);
                acc.y = fmaxf(fmaf(acc.y, sc4.y, sh4.y), 0.f);
                acc.z = fmaxf(fmaf(acc.z, sc4.z, sh4.z), 0.f);
                acc.w = fmaxf(fmaf(acc.w, sc4.w, sh4.w), 0.f);
                __builtin_nontemporal_store(acc, &out4[(long)pj[j] * 16 + q]);  // 1KB/wave seq
            }
        }
    }
}

// ---------------------------------------------------------------- launch
extern "C" void kernel_launch(void* const* d_in, const int* in_sizes, int n_in,
                              void* d_out, int out_size, void* d_ws, size_t ws_size,
                              hipStream_t stream)
{
    const float* feats  = (const float*)d_in[0];
    const float* weight = (const float*)d_in[1];   // [9][1][64]
    const float* gamma  = (const float*)d_in[2];
    const float* beta   = (const float*)d_in[3];
    const int2*  coords = (const int2*)d_in[4];    // [N][2] (y,x)
    float*       out    = (float*)d_out;
    int N = in_sizes[0];                           // C_IN == 1

    float*         ws    = (float*)d_ws;
    float*         grid  = ws;
    unsigned char* mask  = (unsigned char*)(ws + MASK_OFFF);
    float*         stats = ws + STATS_OFFF;

    // zero grid + mask + stats accumulators (ws is poisoned 0xAA)
    (void)hipMemsetAsync(d_ws, 0, (size_t)ZERO_FLOATS * sizeof(float), stream);

    scatter_k    <<<(N + 255) / 256, 256, 0, stream>>>(feats, coords, grid, mask, N);
    stats_dense_k<<<1024, 256, 0, stream>>>(grid, mask, stats);
    out_point_k  <<<4096, 256, 0, stream>>>(grid, coords, weight, stats, gamma, beta, out, N);
}